// Round 14
// baseline (144.444 us; speedup 1.0000x reference)
//
#include <hip/hip_runtime.h>

// Problem collapses: output = classifier(node 0) only.
//   out = dot(wc, mean(pool(lrelu(conv3(p2)+b3)))) + bc
//   p2  = pool(lrelu(conv2(12*P1) + 4*b2))   (node 1, indeg=4)
//   P1  = pool(lrelu(conv1(x)+b1))           (sum indegs over {0,2,4,6} = 12)
//
// R14: k2 grid fix -- cog(8x8co) x rs(4x8rows) = 1024 blocks (4/CU, was 2);
// waves own 2 co fully (no combine), lanes own 4 cols x 1 row; LDS 26.4 KB.
// k1/k3 as R13. Full-line stores, LDS weight broadcast, haloed layouts.

#define LRELU(v) fmaxf((v), 0.2f * (v))

#define P1H_ELEMS (32 * 32 * 34 * 36)
#define P2H_ELEMS (32 * 64 * 18 * 20)

// ---------- k1: conv1 4->32 @64x64, +b1, lrelu, pool2, *12 -> P1H ----------
__global__ __launch_bounds__(256, 4) void k1(const float* __restrict__ x,
                                             const float* __restrict__ w1,
                                             const float* __restrict__ b1,
                                             float* __restrict__ P1H,
                                             float* __restrict__ out) {
    __shared__ __align__(16) float obuf[1152];     // [4co][8prow][36]
    const int bx = blockIdx.x;                     // 32 = rb(4) x cog(8)
    const int b  = blockIdx.y;
    const int rb = bx & 3, cog = bx >> 2;
    const int t  = threadIdx.x;
    const int l  = t & 63, wv = t >> 6;
    const int r  = l >> 4, q = l & 15;
    const int row0 = 16 * rb + 4 * wv + r;         // pre-pool row 0..63

    if (bx == 0 && t == 0) out[b] = 0.f;           // k3 atomics ordered after

    for (int i = t; i < 288; i += 256)
        *(float4*)&obuf[4 * i] = make_float4(0.f, 0.f, 0.f, 0.f);
    __syncthreads();

    const bool cL = (q > 0), cR = (q < 15);
    const int colL = max(4 * q - 2, 0);
    const int colR = min(4 * q + 4, 62);

    float acc[4][4];
    #pragma unroll
    for (int g = 0; g < 4; ++g) {
        float bias = b1[cog * 4 + g];
        acc[g][0] = bias; acc[g][1] = bias; acc[g][2] = bias; acc[g][3] = bias;
    }

    #pragma unroll
    for (int c = 0; c < 4; ++c) {
        float win[3][6];
        #pragma unroll
        for (int d = 0; d < 3; ++d) {
            int gr = row0 - 1 + d;
            bool v = (unsigned)gr < 64u;
            int grc = min(max(gr, 0), 63);
            const float* row = x + ((b * 4 + c) * 64 + grc) * 64;
            float2 L  = *(const float2*)(row + colL);
            float4 M  = *(const float4*)(row + 4 * q);
            float2 R2 = *(const float2*)(row + colR);
            win[d][0] = (v && cL) ? L.y : 0.f;
            win[d][1] = v ? M.x : 0.f;
            win[d][2] = v ? M.y : 0.f;
            win[d][3] = v ? M.z : 0.f;
            win[d][4] = v ? M.w : 0.f;
            win[d][5] = (v && cR) ? R2.x : 0.f;
        }
        #pragma unroll
        for (int g = 0; g < 4; ++g) {
            const float* wp = &w1[((cog * 4 + g) * 4 + c) * 9];  // tiny K$ set
            #pragma unroll
            for (int d = 0; d < 3; ++d)
                #pragma unroll
                for (int j = 0; j < 3; ++j) {
                    float w = wp[3 * d + j];
                    acc[g][0] += w * win[d][j];
                    acc[g][1] += w * win[d][j + 1];
                    acc[g][2] += w * win[d][j + 2];
                    acc[g][3] += w * win[d][j + 3];
                }
        }
    }

    const int prow_l = 2 * wv + (r >> 1);
    #pragma unroll
    for (int g = 0; g < 4; ++g) {
        float m0 = fmaxf(LRELU(acc[g][0]), LRELU(acc[g][1]));
        float m1 = fmaxf(LRELU(acc[g][2]), LRELU(acc[g][3]));
        float p0 = fmaxf(m0, __shfl_xor(m0, 16));
        float p1 = fmaxf(m1, __shfl_xor(m1, 16));
        if ((r & 1) == 0) {
            obuf[(g * 8 + prow_l) * 36 + 2 * q + 1] = 12.f * p0;
            obuf[(g * 8 + prow_l) * 36 + 2 * q + 2] = 12.f * p1;
        }
    }
    __syncthreads();

    for (int i = t; i < 288; i += 256) {
        int co_l = i / 72, rem = i % 72, pr = rem / 9, cw = rem % 9;
        *(float4*)&P1H[((b * 32 + cog * 4 + co_l) * 34 + 8 * rb + pr + 1) * 36 + 4 * cw] =
            *(const float4*)&obuf[4 * i];
    }
    if (rb == 0 || rb == 3) {
        int h = rb ? 33 : 0;
        for (int i = t; i < 36; i += 256) {
            int co_l = i / 9, cw = i % 9;
            *(float4*)&P1H[((b * 32 + cog * 4 + co_l) * 34 + h) * 36 + 4 * cw] =
                make_float4(0.f, 0.f, 0.f, 0.f);
        }
    }
}

// ---------- k2: conv2 32->64 @32x32, +4*b2, lrelu, pool2 -> p2H ------------
// block = cog(8 x 8co) x rs(4 x 8rows); waves own 2 co fully; 1024 blocks.
__global__ __launch_bounds__(256, 4) void k2(const float* __restrict__ P1H,
                                             const float* __restrict__ w2,
                                             const float* __restrict__ b2,
                                             float* __restrict__ p2H) {
    __shared__ __align__(16) float wtile[3072];    // [8co][32cin][12] 12.3 KB
    __shared__ __align__(16) float xin[2880];      // [8cin][10row][36] 11.5 KB
    __shared__ __align__(16) float obuf[640];      // [8co][4prow][20]   2.6 KB
    const int bx = blockIdx.x;                     // 32 = cog(8) x rs(4)
    const int b  = blockIdx.y;
    const int cog = bx >> 2, rs = bx & 3;
    const int c0  = cog * 8;
    const int t  = threadIdx.x, l = t & 63;
    const int wvs = __builtin_amdgcn_readfirstlane(t >> 6);
    const int q  = l & 7, R = l >> 3;              // cols 4q..4q+3; row rs*8+R

    // stage weights: contiguous float4 reads, scatter to stride-12 (pad 9->12)
    for (int i = t; i < 576; i += 256) {           // 8co x 32cin x 9 = 2304 fl
        float4 v = *(const float4*)&w2[cog * 2304 + 4 * i];
        int e = 4 * i;
        wtile[((e + 0) / 9) * 12 + (e + 0) % 9] = v.x;
        wtile[((e + 1) / 9) * 12 + (e + 1) % 9] = v.y;
        wtile[((e + 2) / 9) * 12 + (e + 2) % 9] = v.z;
        wtile[((e + 3) / 9) * 12 + (e + 3) % 9] = v.w;
    }
    for (int i = t; i < 160; i += 256)
        *(float4*)&obuf[4 * i] = make_float4(0.f, 0.f, 0.f, 0.f);

    float acc[2][4];
    #pragma unroll
    for (int g = 0; g < 2; ++g) {
        float bias = 4.f * b2[c0 + wvs * 2 + g];   // wave owns these co fully
        acc[g][0] = bias; acc[g][1] = bias; acc[g][2] = bias; acc[g][3] = bias;
    }

    for (int cc = 0; cc < 4; ++cc) {
        __syncthreads();
        for (int i = t; i < 720; i += 256) {       // 8 cin x 10 rows x 9 f4
            int cin_l = i / 90, rem = i % 90;
            *(float4*)&xin[cin_l * 360 + 4 * rem] =
                *(const float4*)&P1H[((b * 32 + cc * 8 + cin_l) * 34 + rs * 8) * 36 + 4 * rem];
        }
        __syncthreads();
        #pragma unroll
        for (int cl = 0; cl < 8; ++cl) {
            float win[3][6];
            #pragma unroll
            for (int d = 0; d < 3; ++d) {
                const float* xr = &xin[cl * 360 + (R + d) * 36 + 4 * q];
                float4 M  = *(const float4*)xr;
                float2 Rt = *(const float2*)(xr + 4);
                win[d][0] = M.x; win[d][1] = M.y; win[d][2] = M.z;
                win[d][3] = M.w; win[d][4] = Rt.x; win[d][5] = Rt.y;
            }
            const int cin = cc * 8 + cl;
            #pragma unroll
            for (int g = 0; g < 2; ++g) {
                const float* wg = &wtile[((wvs * 2 + g) * 32 + cin) * 12];
                float4 wa = *(const float4*)wg;
                float4 wb = *(const float4*)(wg + 4);
                float  w8 = wg[8];
                float wt[9] = {wa.x, wa.y, wa.z, wa.w, wb.x, wb.y, wb.z, wb.w, w8};
                #pragma unroll
                for (int d = 0; d < 3; ++d)
                    #pragma unroll
                    for (int j = 0; j < 3; ++j) {
                        float w = wt[3 * d + j];
                        acc[g][0] += w * win[d][j];
                        acc[g][1] += w * win[d][j + 1];
                        acc[g][2] += w * win[d][j + 2];
                        acc[g][3] += w * win[d][j + 3];
                    }
            }
        }
    }

    // pool: col pairs in-lane; row pair via shfl_xor(8) (R <-> R^1)
    #pragma unroll
    for (int g = 0; g < 2; ++g) {
        float m0 = fmaxf(LRELU(acc[g][0]), LRELU(acc[g][1]));
        float m1 = fmaxf(LRELU(acc[g][2]), LRELU(acc[g][3]));
        float p0 = fmaxf(m0, __shfl_xor(m0, 8));
        float p1 = fmaxf(m1, __shfl_xor(m1, 8));
        if ((R & 1) == 0) {
            int co_l = wvs * 2 + g;
            obuf[(co_l * 4 + (R >> 1)) * 20 + 2 * q + 1] = p0;
            obuf[(co_l * 4 + (R >> 1)) * 20 + 2 * q + 2] = p1;
        }
    }
    __syncthreads();

    // full-line coalesced stores (80 B rows incl. halo cols)
    for (int i = t; i < 160; i += 256) {           // 8co x 4prow x 5 f4
        int co_l = i / 20, rem = i % 20, pr = rem / 5, cw = rem % 5;
        *(float4*)&p2H[((b * 64 + c0 + co_l) * 18 + rs * 4 + pr + 1) * 20 + 4 * cw] =
            *(const float4*)&obuf[4 * i];
    }
    if (rs == 0 || rs == 3) {
        int h2 = rs ? 17 : 0;
        for (int i = t; i < 40; i += 256) {        // 8co x 5 f4
            int co_l = i / 5, cw = i % 5;
            *(float4*)&p2H[((b * 64 + c0 + co_l) * 18 + h2) * 20 + 4 * cw] =
                make_float4(0.f, 0.f, 0.f, 0.f);
        }
    }
}

// ---------- k3: conv3 64->128 @16x16, +b3, lrelu, pool2, mean, dot ---------
// block = 4-co group (32 of them, 1024 blocks = 4/CU); waves split cin.
__global__ __launch_bounds__(256, 4) void k3(const float* __restrict__ p2H,
                                             const float* __restrict__ w3,
                                             const float* __restrict__ b3,
                                             const float* __restrict__ wc,
                                             const float* __restrict__ bc,
                                             float* __restrict__ out) {
    __shared__ __align__(16) float smem[3072];   // wtile [4co][64][12]; cbuf stride16
    const int cog = blockIdx.x;                  // 0..31 -> 4 co
    const int b   = blockIdx.y;
    const int c0  = cog * 4;
    const int t   = threadIdx.x, l = t & 63;
    const int wvs = __builtin_amdgcn_readfirstlane(t >> 6);
    const int r   = l >> 2, q = l & 3;

    for (int i = t; i < 576; i += 256) {         // 4co x 64cin x 9 = 2304 fl
        float4 v = *(const float4*)&w3[cog * 2304 + 4 * i];
        int e = 4 * i;
        smem[((e + 0) / 9) * 12 + (e + 0) % 9] = v.x;
        smem[((e + 1) / 9) * 12 + (e + 1) % 9] = v.y;
        smem[((e + 2) / 9) * 12 + (e + 2) % 9] = v.z;
        smem[((e + 3) / 9) * 12 + (e + 3) % 9] = v.w;
    }
    __syncthreads();

    float acc[4][4];
    #pragma unroll
    for (int g = 0; g < 4; ++g) {
        float bias = (wvs == 0) ? b3[c0 + g] : 0.f;
        acc[g][0] = bias; acc[g][1] = bias; acc[g][2] = bias; acc[g][3] = bias;
    }

    #pragma unroll
    for (int cl = 0; cl < 16; ++cl) {
        const int cin = wvs * 16 + cl;
        const float* pb = p2H + (((b * 64 + cin) * 18 + r) * 20 + 4 * q);
        float win[3][6];
        #pragma unroll
        for (int d = 0; d < 3; ++d) {
            float4 M  = *(const float4*)(pb + d * 20);
            float2 Rt = *(const float2*)(pb + d * 20 + 4);
            win[d][0] = M.x; win[d][1] = M.y; win[d][2] = M.z;
            win[d][3] = M.w; win[d][4] = Rt.x; win[d][5] = Rt.y;
        }
        #pragma unroll
        for (int g = 0; g < 4; ++g) {
            const float* wg = &smem[(g * 64 + cin) * 12];
            float4 wa = *(const float4*)wg;
            float4 wb = *(const float4*)(wg + 4);
            float  w8 = wg[8];
            float wt[9] = {wa.x, wa.y, wa.z, wa.w, wb.x, wb.y, wb.z, wb.w, w8};
            #pragma unroll
            for (int d = 0; d < 3; ++d)
                #pragma unroll
                for (int j = 0; j < 3; ++j) {
                    float w = wt[3 * d + j];
                    acc[g][0] += w * win[d][j];
                    acc[g][1] += w * win[d][j + 1];
                    acc[g][2] += w * win[d][j + 2];
                    acc[g][3] += w * win[d][j + 3];
                }
        }
    }

    __syncthreads();   // weights dead; smem becomes combine buffer (stride 16)
    if (wvs > 0) {
        float* cb = &smem[((wvs - 1) * 64 + l) * 16];
        #pragma unroll
        for (int g = 0; g < 4; ++g)
            *(float4*)&cb[g * 4] =
                make_float4(acc[g][0], acc[g][1], acc[g][2], acc[g][3]);
    }
    __syncthreads();

    if (wvs == 0) {
        #pragma unroll
        for (int k = 0; k < 3; ++k) {
            const float* cb = &smem[(k * 64 + l) * 16];
            #pragma unroll
            for (int g = 0; g < 4; ++g) {
                float4 v = *(const float4*)&cb[g * 4];
                acc[g][0] += v.x; acc[g][1] += v.y;
                acc[g][2] += v.z; acc[g][3] += v.w;
            }
        }
        float vsum = 0.f;
        #pragma unroll
        for (int g = 0; g < 4; ++g) {
            float m0 = fmaxf(LRELU(acc[g][0]), LRELU(acc[g][1]));
            float m1 = fmaxf(LRELU(acc[g][2]), LRELU(acc[g][3]));
            float pm0 = fmaxf(m0, __shfl_xor(m0, 4));
            float pm1 = fmaxf(m1, __shfl_xor(m1, 4));
            float contrib = ((r & 1) == 0) ? (pm0 + pm1) : 0.f;
            vsum += contrib * wc[c0 + g];
        }
        #pragma unroll
        for (int off = 32; off > 0; off >>= 1) vsum += __shfl_xor(vsum, off);
        if (l == 0) {
            float o = vsum * (1.f / 64.f);
            if (cog == 0) o += bc[0];
            atomicAdd(&out[b], o);
        }
    }
}

extern "C" void kernel_launch(void* const* d_in, const int* in_sizes, int n_in,
                              void* d_out, int out_size, void* d_ws, size_t ws_size,
                              hipStream_t stream) {
    const float* x  = (const float*)d_in[0];
    const float* w1 = (const float*)d_in[1];
    const float* b1 = (const float*)d_in[2];
    const float* w2 = (const float*)d_in[3];
    const float* b2 = (const float*)d_in[4];
    const float* w3 = (const float*)d_in[5];
    const float* b3 = (const float*)d_in[6];
    const float* wc = (const float*)d_in[7];
    const float* bc = (const float*)d_in[8];
    float* out = (float*)d_out;

    float* P1H = (float*)d_ws;                    // [32][32][34][36] ~5.4 MB
    float* p2H = P1H + P1H_ELEMS;                 // [32][64][18][20] ~2.8 MB

    k1<<<dim3(32, 32), 256, 0, stream>>>(x, w1, b1, P1H, out);
    k2<<<dim3(32, 32), 256, 0, stream>>>(P1H, w2, b2, p2H);
    k3<<<dim3(32, 32), 256, 0, stream>>>(p2H, w3, b3, wc, bc, out);
}

// Round 15
// 137.830 us; speedup vs baseline: 1.0480x; 1.0480x over previous
//
#include <hip/hip_runtime.h>

// Problem collapses: output = classifier(node 0) only.
//   out = dot(wc, mean(pool(lrelu(conv3(p2)+b3)))) + bc
//   p2  = pool(lrelu(conv2(12*P1) + 4*b2))   (node 1, indeg=4)
//   P1  = pool(lrelu(conv1(x)+b1))           (sum indegs over {0,2,4,6} = 12)
//
// R15 = revert to R13 (best measured, 136.3 us). R14's k2 8-cog split
// doubled P1H re-reads and regressed; R13's k2 = 4 cog x 16 co x 4 row
// strips is the traffic sweet spot. Full-line stores, LDS weight broadcast
// with immediate offsets, haloed intermediate layouts.

#define LRELU(v) fmaxf((v), 0.2f * (v))

#define P1H_ELEMS (32 * 32 * 34 * 36)
#define P2H_ELEMS (32 * 64 * 18 * 20)

// ---------- k1: conv1 4->32 @64x64, +b1, lrelu, pool2, *12 -> P1H ----------
__global__ __launch_bounds__(256, 4) void k1(const float* __restrict__ x,
                                             const float* __restrict__ w1,
                                             const float* __restrict__ b1,
                                             float* __restrict__ P1H,
                                             float* __restrict__ out) {
    __shared__ __align__(16) float obuf[1152];     // [4co][8prow][36]
    const int bx = blockIdx.x;                     // 32 = rb(4) x cog(8)
    const int b  = blockIdx.y;
    const int rb = bx & 3, cog = bx >> 2;
    const int t  = threadIdx.x;
    const int l  = t & 63, wv = t >> 6;
    const int r  = l >> 4, q = l & 15;
    const int row0 = 16 * rb + 4 * wv + r;         // pre-pool row 0..63

    if (bx == 0 && t == 0) out[b] = 0.f;           // k3 atomics ordered after

    for (int i = t; i < 288; i += 256)
        *(float4*)&obuf[4 * i] = make_float4(0.f, 0.f, 0.f, 0.f);
    __syncthreads();

    const bool cL = (q > 0), cR = (q < 15);
    const int colL = max(4 * q - 2, 0);
    const int colR = min(4 * q + 4, 62);

    float acc[4][4];
    #pragma unroll
    for (int g = 0; g < 4; ++g) {
        float bias = b1[cog * 4 + g];
        acc[g][0] = bias; acc[g][1] = bias; acc[g][2] = bias; acc[g][3] = bias;
    }

    #pragma unroll
    for (int c = 0; c < 4; ++c) {
        float win[3][6];
        #pragma unroll
        for (int d = 0; d < 3; ++d) {
            int gr = row0 - 1 + d;
            bool v = (unsigned)gr < 64u;
            int grc = min(max(gr, 0), 63);
            const float* row = x + ((b * 4 + c) * 64 + grc) * 64;
            float2 L  = *(const float2*)(row + colL);
            float4 M  = *(const float4*)(row + 4 * q);
            float2 R2 = *(const float2*)(row + colR);
            win[d][0] = (v && cL) ? L.y : 0.f;
            win[d][1] = v ? M.x : 0.f;
            win[d][2] = v ? M.y : 0.f;
            win[d][3] = v ? M.z : 0.f;
            win[d][4] = v ? M.w : 0.f;
            win[d][5] = (v && cR) ? R2.x : 0.f;
        }
        #pragma unroll
        for (int g = 0; g < 4; ++g) {
            const float* wp = &w1[((cog * 4 + g) * 4 + c) * 9];  // tiny K$ set
            #pragma unroll
            for (int d = 0; d < 3; ++d)
                #pragma unroll
                for (int j = 0; j < 3; ++j) {
                    float w = wp[3 * d + j];
                    acc[g][0] += w * win[d][j];
                    acc[g][1] += w * win[d][j + 1];
                    acc[g][2] += w * win[d][j + 2];
                    acc[g][3] += w * win[d][j + 3];
                }
        }
    }

    const int prow_l = 2 * wv + (r >> 1);
    #pragma unroll
    for (int g = 0; g < 4; ++g) {
        float m0 = fmaxf(LRELU(acc[g][0]), LRELU(acc[g][1]));
        float m1 = fmaxf(LRELU(acc[g][2]), LRELU(acc[g][3]));
        float p0 = fmaxf(m0, __shfl_xor(m0, 16));
        float p1 = fmaxf(m1, __shfl_xor(m1, 16));
        if ((r & 1) == 0) {
            obuf[(g * 8 + prow_l) * 36 + 2 * q + 1] = 12.f * p0;
            obuf[(g * 8 + prow_l) * 36 + 2 * q + 2] = 12.f * p1;
        }
    }
    __syncthreads();

    for (int i = t; i < 288; i += 256) {
        int co_l = i / 72, rem = i % 72, pr = rem / 9, cw = rem % 9;
        *(float4*)&P1H[((b * 32 + cog * 4 + co_l) * 34 + 8 * rb + pr + 1) * 36 + 4 * cw] =
            *(const float4*)&obuf[4 * i];
    }
    if (rb == 0 || rb == 3) {
        int h = rb ? 33 : 0;
        for (int i = t; i < 36; i += 256) {
            int co_l = i / 9, cw = i % 9;
            *(float4*)&P1H[((b * 32 + cog * 4 + co_l) * 34 + h) * 36 + 4 * cw] =
                make_float4(0.f, 0.f, 0.f, 0.f);
        }
    }
}

// ---------- k2: conv2 32->64 @32x32, +4*b2, lrelu, pool2 -> p2H ------------
// block = (cog 4 x 16co) x (rs 4 x 8rows); waves split CO (4 each, full cin
// sum, no combine). Lanes own 4 cols x 1 row.
__global__ __launch_bounds__(256, 2) void k2(const float* __restrict__ P1H,
                                             const float* __restrict__ w2,
                                             const float* __restrict__ b2,
                                             float* __restrict__ p2H) {
    __shared__ __align__(16) float wtile[6144];    // [16co][32cin][12] 24.6 KB
    __shared__ __align__(16) float xin[2880];      // [8cin][10row][36] 11.5 KB
    __shared__ __align__(16) float obuf[1280];     // [16co][4prow][20]  5.1 KB
    const int bx = blockIdx.x;                     // 16 = cog(4) x rs(4)
    const int b  = blockIdx.y;
    const int cog = bx >> 2, rs = bx & 3;
    const int c0  = cog * 16;
    const int t  = threadIdx.x, l = t & 63;
    const int wvs = __builtin_amdgcn_readfirstlane(t >> 6);
    const int q  = l & 7, R = l >> 3;              // cols 4q..4q+3; row rs*8+R

    // stage weights: contiguous float4 reads, scatter to stride-12 (pad 9->12)
    for (int i = t; i < 1152; i += 256) {
        float4 v = *(const float4*)&w2[cog * 4608 + 4 * i];
        int e = 4 * i;
        wtile[((e + 0) / 9) * 12 + (e + 0) % 9] = v.x;
        wtile[((e + 1) / 9) * 12 + (e + 1) % 9] = v.y;
        wtile[((e + 2) / 9) * 12 + (e + 2) % 9] = v.z;
        wtile[((e + 3) / 9) * 12 + (e + 3) % 9] = v.w;
    }
    for (int i = t; i < 320; i += 256)
        *(float4*)&obuf[4 * i] = make_float4(0.f, 0.f, 0.f, 0.f);

    float acc[4][4];
    #pragma unroll
    for (int g = 0; g < 4; ++g) {
        float bias = 4.f * b2[c0 + wvs * 4 + g];   // wave owns these co fully
        acc[g][0] = bias; acc[g][1] = bias; acc[g][2] = bias; acc[g][3] = bias;
    }

    for (int cc = 0; cc < 4; ++cc) {
        __syncthreads();
        for (int i = t; i < 720; i += 256) {       // 8 cin x 10 rows x 9 f4
            int cin_l = i / 90, rem = i % 90;
            *(float4*)&xin[cin_l * 360 + 4 * rem] =
                *(const float4*)&P1H[((b * 32 + cc * 8 + cin_l) * 34 + rs * 8) * 36 + 4 * rem];
        }
        __syncthreads();
        #pragma unroll
        for (int cl = 0; cl < 8; ++cl) {
            float win[3][6];
            #pragma unroll
            for (int d = 0; d < 3; ++d) {
                const float* xr = &xin[cl * 360 + (R + d) * 36 + 4 * q];
                float4 M  = *(const float4*)xr;
                float2 Rt = *(const float2*)(xr + 4);
                win[d][0] = M.x; win[d][1] = M.y; win[d][2] = M.z;
                win[d][3] = M.w; win[d][4] = Rt.x; win[d][5] = Rt.y;
            }
            const int cin = cc * 8 + cl;
            #pragma unroll
            for (int g = 0; g < 4; ++g) {
                const float* wg = &wtile[((wvs * 4 + g) * 32 + cin) * 12];
                float4 wa = *(const float4*)wg;
                float4 wb = *(const float4*)(wg + 4);
                float  w8 = wg[8];
                float wt[9] = {wa.x, wa.y, wa.z, wa.w, wb.x, wb.y, wb.z, wb.w, w8};
                #pragma unroll
                for (int d = 0; d < 3; ++d)
                    #pragma unroll
                    for (int j = 0; j < 3; ++j) {
                        float w = wt[3 * d + j];
                        acc[g][0] += w * win[d][j];
                        acc[g][1] += w * win[d][j + 1];
                        acc[g][2] += w * win[d][j + 2];
                        acc[g][3] += w * win[d][j + 3];
                    }
            }
        }
    }

    // pool: col pairs in-lane; row pair via shfl_xor(8) (R <-> R^1)
    #pragma unroll
    for (int g = 0; g < 4; ++g) {
        float m0 = fmaxf(LRELU(acc[g][0]), LRELU(acc[g][1]));
        float m1 = fmaxf(LRELU(acc[g][2]), LRELU(acc[g][3]));
        float p0 = fmaxf(m0, __shfl_xor(m0, 8));
        float p1 = fmaxf(m1, __shfl_xor(m1, 8));
        if ((R & 1) == 0) {
            int co_l = wvs * 4 + g;
            obuf[(co_l * 4 + (R >> 1)) * 20 + 2 * q + 1] = p0;
            obuf[(co_l * 4 + (R >> 1)) * 20 + 2 * q + 2] = p1;
        }
    }
    __syncthreads();

    // full-line coalesced stores (80 B rows incl. halo cols)
    for (int i = t; i < 320; i += 256) {
        int co_l = i / 20, rem = i % 20, pr = rem / 5, cw = rem % 5;
        *(float4*)&p2H[((b * 64 + c0 + co_l) * 18 + rs * 4 + pr + 1) * 20 + 4 * cw] =
            *(const float4*)&obuf[4 * i];
    }
    if (rs == 0 || rs == 3) {
        int h2 = rs ? 17 : 0;
        for (int i = t; i < 80; i += 256) {
            int co_l = i / 5, cw = i % 5;
            *(float4*)&p2H[((b * 64 + c0 + co_l) * 18 + h2) * 20 + 4 * cw] =
                make_float4(0.f, 0.f, 0.f, 0.f);
        }
    }
}

// ---------- k3: conv3 64->128 @16x16, +b3, lrelu, pool2, mean, dot ---------
// block = 4-co group (32 of them, 1024 blocks = 4/CU); waves split cin.
__global__ __launch_bounds__(256, 4) void k3(const float* __restrict__ p2H,
                                             const float* __restrict__ w3,
                                             const float* __restrict__ b3,
                                             const float* __restrict__ wc,
                                             const float* __restrict__ bc,
                                             float* __restrict__ out) {
    __shared__ __align__(16) float smem[3072];   // wtile [4co][64][12]; cbuf stride16
    const int cog = blockIdx.x;                  // 0..31 -> 4 co
    const int b   = blockIdx.y;
    const int c0  = cog * 4;
    const int t   = threadIdx.x, l = t & 63;
    const int wvs = __builtin_amdgcn_readfirstlane(t >> 6);
    const int r   = l >> 2, q = l & 3;

    for (int i = t; i < 576; i += 256) {         // 4co x 64cin x 9 = 2304 fl
        float4 v = *(const float4*)&w3[cog * 2304 + 4 * i];
        int e = 4 * i;
        smem[((e + 0) / 9) * 12 + (e + 0) % 9] = v.x;
        smem[((e + 1) / 9) * 12 + (e + 1) % 9] = v.y;
        smem[((e + 2) / 9) * 12 + (e + 2) % 9] = v.z;
        smem[((e + 3) / 9) * 12 + (e + 3) % 9] = v.w;
    }
    __syncthreads();

    float acc[4][4];
    #pragma unroll
    for (int g = 0; g < 4; ++g) {
        float bias = (wvs == 0) ? b3[c0 + g] : 0.f;
        acc[g][0] = bias; acc[g][1] = bias; acc[g][2] = bias; acc[g][3] = bias;
    }

    #pragma unroll
    for (int cl = 0; cl < 16; ++cl) {
        const int cin = wvs * 16 + cl;
        const float* pb = p2H + (((b * 64 + cin) * 18 + r) * 20 + 4 * q);
        float win[3][6];
        #pragma unroll
        for (int d = 0; d < 3; ++d) {
            float4 M  = *(const float4*)(pb + d * 20);
            float2 Rt = *(const float2*)(pb + d * 20 + 4);
            win[d][0] = M.x; win[d][1] = M.y; win[d][2] = M.z;
            win[d][3] = M.w; win[d][4] = Rt.x; win[d][5] = Rt.y;
        }
        #pragma unroll
        for (int g = 0; g < 4; ++g) {
            const float* wg = &smem[(g * 64 + cin) * 12];
            float4 wa = *(const float4*)wg;
            float4 wb = *(const float4*)(wg + 4);
            float  w8 = wg[8];
            float wt[9] = {wa.x, wa.y, wa.z, wa.w, wb.x, wb.y, wb.z, wb.w, w8};
            #pragma unroll
            for (int d = 0; d < 3; ++d)
                #pragma unroll
                for (int j = 0; j < 3; ++j) {
                    float w = wt[3 * d + j];
                    acc[g][0] += w * win[d][j];
                    acc[g][1] += w * win[d][j + 1];
                    acc[g][2] += w * win[d][j + 2];
                    acc[g][3] += w * win[d][j + 3];
                }
        }
    }

    __syncthreads();   // weights dead; smem becomes combine buffer (stride 16)
    if (wvs > 0) {
        float* cb = &smem[((wvs - 1) * 64 + l) * 16];
        #pragma unroll
        for (int g = 0; g < 4; ++g)
            *(float4*)&cb[g * 4] =
                make_float4(acc[g][0], acc[g][1], acc[g][2], acc[g][3]);
    }
    __syncthreads();

    if (wvs == 0) {
        #pragma unroll
        for (int k = 0; k < 3; ++k) {
            const float* cb = &smem[(k * 64 + l) * 16];
            #pragma unroll
            for (int g = 0; g < 4; ++g) {
                float4 v = *(const float4*)&cb[g * 4];
                acc[g][0] += v.x; acc[g][1] += v.y;
                acc[g][2] += v.z; acc[g][3] += v.w;
            }
        }
        float vsum = 0.f;
        #pragma unroll
        for (int g = 0; g < 4; ++g) {
            float m0 = fmaxf(LRELU(acc[g][0]), LRELU(acc[g][1]));
            float m1 = fmaxf(LRELU(acc[g][2]), LRELU(acc[g][3]));
            float pm0 = fmaxf(m0, __shfl_xor(m0, 4));
            float pm1 = fmaxf(m1, __shfl_xor(m1, 4));
            float contrib = ((r & 1) == 0) ? (pm0 + pm1) : 0.f;
            vsum += contrib * wc[c0 + g];
        }
        #pragma unroll
        for (int off = 32; off > 0; off >>= 1) vsum += __shfl_xor(vsum, off);
        if (l == 0) {
            float o = vsum * (1.f / 64.f);
            if (cog == 0) o += bc[0];
            atomicAdd(&out[b], o);
        }
    }
}

extern "C" void kernel_launch(void* const* d_in, const int* in_sizes, int n_in,
                              void* d_out, int out_size, void* d_ws, size_t ws_size,
                              hipStream_t stream) {
    const float* x  = (const float*)d_in[0];
    const float* w1 = (const float*)d_in[1];
    const float* b1 = (const float*)d_in[2];
    const float* w2 = (const float*)d_in[3];
    const float* b2 = (const float*)d_in[4];
    const float* w3 = (const float*)d_in[5];
    const float* b3 = (const float*)d_in[6];
    const float* wc = (const float*)d_in[7];
    const float* bc = (const float*)d_in[8];
    float* out = (float*)d_out;

    float* P1H = (float*)d_ws;                    // [32][32][34][36] ~5.4 MB
    float* p2H = P1H + P1H_ELEMS;                 // [32][64][18][20] ~2.8 MB

    k1<<<dim3(32, 32), 256, 0, stream>>>(x, w1, b1, P1H, out);
    k2<<<dim3(16, 32), 256, 0, stream>>>(P1H, w2, b2, p2H);
    k3<<<dim3(32, 32), 256, 0, stream>>>(p2H, w3, b3, wc, bc, out);
}